// Round 2
// baseline (618.481 us; speedup 1.0000x reference)
//
#include <hip/hip_runtime.h>
#include <hip/hip_bf16.h>

#define N_NODES 100000
#define N_EDGES 3200000
#define NFEAT 256
#define NHID 128
#define NCLASS 64
#define SCAN_B 1024
#define NB_SCAN ((N_NODES + SCAN_B - 1) / SCAN_B)   // 98
#define NVEC4 (N_EDGES / 4)                          // 800000
#define RANGE (N_NODES / 8)                          // 12500 nodes per group
#define NSL 64                                       // edge slices per group

typedef unsigned int uint32;
typedef unsigned short ushort16;

// hand-rolled bf16 (RNE) — intermediates only, finite values
static __device__ __forceinline__ float b2f(ushort16 u) {
    union { float f; uint32 i; } c; c.i = ((uint32)u) << 16; return c.f;
}
static __device__ __forceinline__ ushort16 f2b(float f) {
    union { float f; uint32 i; } c; c.f = f;
    uint32 r = (c.i + 0x7FFFu + ((c.i >> 16) & 1u)) >> 16;
    return (ushort16)r;
}
// unpack bf16 pair packed in a uint32 (little-endian: low ushort = even class)
static __device__ __forceinline__ float blo(uint32 u) {
    union { float f; uint32 i; } c; c.i = u << 16; return c.f;
}
static __device__ __forceinline__ float bhi(uint32 u) {
    union { float f; uint32 i; } c; c.i = u & 0xFFFF0000u; return c.f;
}

// ---------------- phase A: LDS-privatized histogram ----------------
__global__ __launch_bounds__(256) void k_hist(const int4* __restrict__ src4,
                                              const int4* __restrict__ dst4,
                                              uint32* __restrict__ scratch) {
    __shared__ uint32 h[RANGE];   // 50 KB
    int g = blockIdx.x & 7, sl = blockIdx.x >> 3;
    int lo = g * RANGE, hi = lo + RANGE;
    for (int i = threadIdx.x; i < RANGE; i += 256) h[i] = 0u;
    __syncthreads();
    for (int t = sl * 256 + threadIdx.x; t < NVEC4; t += NSL * 256) {
        int4 s = src4[t], d = dst4[t];
        if (s.x >= lo && s.x < hi) atomicAdd(&h[s.x - lo], 1u);
        if (s.y >= lo && s.y < hi) atomicAdd(&h[s.y - lo], 1u);
        if (s.z >= lo && s.z < hi) atomicAdd(&h[s.z - lo], 1u);
        if (s.w >= lo && s.w < hi) atomicAdd(&h[s.w - lo], 1u);
        if (d.x >= lo && d.x < hi) atomicAdd(&h[d.x - lo], 65536u);
        if (d.y >= lo && d.y < hi) atomicAdd(&h[d.y - lo], 65536u);
        if (d.z >= lo && d.z < hi) atomicAdd(&h[d.z - lo], 65536u);
        if (d.w >= lo && d.w < hi) atomicAdd(&h[d.w - lo], 65536u);
    }
    __syncthreads();
    uint32* dstp = scratch + ((size_t)(g * NSL + sl)) * RANGE;
    for (int i = threadIdx.x; i < RANGE; i += 256) dstp[i] = h[i];
}

// ---------------- reduce per-block counts -> degrees + norms ----------------
__global__ void k_sumdeg(const uint32* __restrict__ scratch, int* __restrict__ deg_in,
                         float* __restrict__ n_src, float* __restrict__ n_dst) {
    int i = blockIdx.x * blockDim.x + threadIdx.x;
    if (i >= N_NODES) return;
    int g = i / RANGE, r = i - g * RANGE;
    const uint32* base = scratch + (size_t)g * NSL * RANGE + r;
    uint32 so = 0, di = 0;
    for (int s = 0; s < NSL; s++) {
        uint32 v = base[(size_t)s * RANGE];
        so += v & 0xFFFFu;
        di += v >> 16;
    }
    deg_in[i] = (int)di;
    uint32 so1 = so < 1u ? 1u : so;
    uint32 di1 = di < 1u ? 1u : di;
    n_src[i] = rsqrtf((float)so1);
    n_dst[i] = rsqrtf((float)di1);
}

// ---------------- scan (3-pass) over deg_in -> row_ptr ----------------
__global__ void k_scan1(const int* __restrict__ deg_in, int* __restrict__ row_ptr,
                        int* __restrict__ blk_sums) {
    __shared__ int sh[SCAN_B];
    int i = blockIdx.x * SCAN_B + threadIdx.x;
    int v = (i < N_NODES) ? deg_in[i] : 0;
    sh[threadIdx.x] = v;
    __syncthreads();
    for (int o = 1; o < SCAN_B; o <<= 1) {
        int t = 0;
        if ((int)threadIdx.x >= o) t = sh[threadIdx.x - o];
        __syncthreads();
        sh[threadIdx.x] += t;
        __syncthreads();
    }
    if (i < N_NODES) row_ptr[i] = sh[threadIdx.x] - v;   // exclusive within block
    if (threadIdx.x == SCAN_B - 1) blk_sums[blockIdx.x] = sh[SCAN_B - 1];
}

__global__ void k_scan2(int* __restrict__ blk_sums) {
    if (threadIdx.x == 0 && blockIdx.x == 0) {
        int acc = 0;
        for (int b = 0; b < NB_SCAN; b++) { int v = blk_sums[b]; blk_sums[b] = acc; acc += v; }
        blk_sums[NB_SCAN] = acc;
    }
}

__global__ void k_scan3(const int* __restrict__ blk_sums, int* __restrict__ row_ptr) {
    int i = blockIdx.x * SCAN_B + threadIdx.x;
    if (i < N_NODES) row_ptr[i] += blk_sums[blockIdx.x];
    if (i == 0) row_ptr[N_NODES] = blk_sums[NB_SCAN];
}

// ---------------- per-(g,slice) cursor start offsets (in-place on scratch) ----------------
__global__ void k_offsets(uint32* __restrict__ scratch, const int* __restrict__ row_ptr) {
    int i = blockIdx.x * blockDim.x + threadIdx.x;
    if (i >= N_NODES) return;
    int g = i / RANGE, r = i - g * RANGE;
    uint32* base = scratch + (size_t)g * NSL * RANGE + r;
    uint32 run = (uint32)row_ptr[i];
    for (int s = 0; s < NSL; s++) {
        uint32 v = base[(size_t)s * RANGE];
        base[(size_t)s * RANGE] = run;
        run += v >> 16;
    }
}

// ---------------- phase B: atomic-free counting-sort fill ----------------
__global__ __launch_bounds__(256) void k_fill2(const int4* __restrict__ src4,
                                               const int4* __restrict__ dst4,
                                               const uint32* __restrict__ scratch,
                                               int* __restrict__ col) {
    __shared__ uint32 cur[RANGE];   // 50 KB
    int g = blockIdx.x & 7, sl = blockIdx.x >> 3;
    int lo = g * RANGE, hi = lo + RANGE;
    const uint32* base = scratch + ((size_t)(g * NSL + sl)) * RANGE;
    for (int i = threadIdx.x; i < RANGE; i += 256) cur[i] = base[i];
    __syncthreads();
    for (int t = sl * 256 + threadIdx.x; t < NVEC4; t += NSL * 256) {
        int4 s = src4[t], d = dst4[t];
        if (d.x >= lo && d.x < hi) { uint32 p = atomicAdd(&cur[d.x - lo], 1u); col[p] = s.x; }
        if (d.y >= lo && d.y < hi) { uint32 p = atomicAdd(&cur[d.y - lo], 1u); col[p] = s.y; }
        if (d.z >= lo && d.z < hi) { uint32 p = atomicAdd(&cur[d.z - lo], 1u); col[p] = s.z; }
        if (d.w >= lo && d.w < hi) { uint32 p = atomicAdd(&cur[d.w - lo], 1u); col[p] = s.w; }
    }
}

// ---------------- tiny weight-collapse GEMMs ----------------
__global__ void k_w01(const float* __restrict__ W0, const float* __restrict__ W1,
                      float* __restrict__ W01) {
    __shared__ float row[NHID];
    int r = blockIdx.x, c = threadIdx.x;   // 128 threads
    row[c] = W0[r * NHID + c];
    __syncthreads();
    float acc = 0.f;
    for (int k = 0; k < NHID; k++) acc += row[k] * W1[k * NHID + c];
    W01[r * NHID + c] = acc;
}

__global__ void k_wc(const float* __restrict__ W01, const float* __restrict__ W2,
                     float* __restrict__ Wc) {
    __shared__ float row[NHID];
    int r = blockIdx.x, c = threadIdx.x;   // 64 threads
    row[c] = W01[r * NHID + c];
    row[c + 64] = W01[r * NHID + c + 64];
    __syncthreads();
    float acc = 0.f;
    for (int k = 0; k < NHID; k++) acc += row[k] * W2[k * NCLASS + c];
    Wc[r * NCLASS + c] = acc;
}

// bv[0..63] = b0@W1@W2, bv[64..127] = b1@W2
__global__ void k_bv(const float* __restrict__ b0, const float* __restrict__ W1,
                     const float* __restrict__ b1, const float* __restrict__ W2,
                     float* __restrict__ bv) {
    __shared__ float tmp[NHID];
    int c = threadIdx.x;   // 64 threads
    for (int cc = c; cc < NHID; cc += 64) {
        float a = 0.f;
        for (int k = 0; k < NHID; k++) a += b0[k] * W1[k * NHID + cc];
        tmp[cc] = a;
    }
    __syncthreads();
    float a1 = 0.f, a2 = 0.f;
    for (int k = 0; k < NHID; k++) {
        float wv = W2[k * NCLASS + c];
        a1 += tmp[k] * wv;
        a2 += b1[k] * wv;
    }
    bv[c] = a1;
    bv[64 + c] = a2;
}

// ---------------- main GEMM: y = x @ Wc  [N,256]x[256,64], bf16 output ----------------
// No LDS: weights (64 KB total) are read directly from global and stay hot in
// L1/L2 (16 unique float4/wave per 4-k chunk, HW-coalesced). Removing the
// 64 KB w_sh lifts the 2-blocks/CU occupancy cap (was 18%) to VGPR-limited
// (~5 waves/SIMD), which is what hides the streaming x-load latency.
static __device__ __forceinline__ void fma4(float4& a, float xs, const float4& wv) {
    a.x += xs * wv.x; a.y += xs * wv.y; a.z += xs * wv.z; a.w += xs * wv.w;
}
__global__ __launch_bounds__(256) void k_gemm_y(const float* __restrict__ x,
                                                const float* __restrict__ Wc,
                                                ushort16* __restrict__ y) {
    int tid = threadIdx.x;
    int tx = tid & 15, ty = tid >> 4;
    int row0 = blockIdx.x * 64 + ty * 4;
    int c0 = tx * 4;
    int r0 = min(row0 + 0, N_NODES - 1);
    int r1 = min(row0 + 1, N_NODES - 1);
    int r2 = min(row0 + 2, N_NODES - 1);
    int r3 = min(row0 + 3, N_NODES - 1);
    const float* xp0 = x + (size_t)r0 * NFEAT;
    const float* xp1 = x + (size_t)r1 * NFEAT;
    const float* xp2 = x + (size_t)r2 * NFEAT;
    const float* xp3 = x + (size_t)r3 * NFEAT;
    const float* wp = Wc + c0;   // row k of Wc at wp + k*NCLASS
    float4 acc0 = {0, 0, 0, 0}, acc1 = {0, 0, 0, 0}, acc2 = {0, 0, 0, 0}, acc3 = {0, 0, 0, 0};
    float4 xa = *(const float4*)(xp0);
    float4 xb = *(const float4*)(xp1);
    float4 xc = *(const float4*)(xp2);
    float4 xd = *(const float4*)(xp3);
    float4 wa = *(const float4*)(wp + 0 * NCLASS);
    float4 wb = *(const float4*)(wp + 1 * NCLASS);
    float4 wc4 = *(const float4*)(wp + 2 * NCLASS);
    float4 wd = *(const float4*)(wp + 3 * NCLASS);
#pragma unroll 4
    for (int k = 0; k < NFEAT - 4; k += 4) {
        float4 ca = xa, cb = xb, cc = xc, cd = xd;
        float4 va = wa, vb = wb, vc = wc4, vd = wd;
        xa = *(const float4*)(xp0 + k + 4);
        xb = *(const float4*)(xp1 + k + 4);
        xc = *(const float4*)(xp2 + k + 4);
        xd = *(const float4*)(xp3 + k + 4);
        wa = *(const float4*)(wp + (k + 4) * NCLASS);
        wb = *(const float4*)(wp + (k + 5) * NCLASS);
        wc4 = *(const float4*)(wp + (k + 6) * NCLASS);
        wd = *(const float4*)(wp + (k + 7) * NCLASS);
        fma4(acc0, ca.x, va); fma4(acc0, ca.y, vb); fma4(acc0, ca.z, vc); fma4(acc0, ca.w, vd);
        fma4(acc1, cb.x, va); fma4(acc1, cb.y, vb); fma4(acc1, cb.z, vc); fma4(acc1, cb.w, vd);
        fma4(acc2, cc.x, va); fma4(acc2, cc.y, vb); fma4(acc2, cc.z, vc); fma4(acc2, cc.w, vd);
        fma4(acc3, cd.x, va); fma4(acc3, cd.y, vb); fma4(acc3, cd.z, vc); fma4(acc3, cd.w, vd);
    }
    {
        fma4(acc0, xa.x, wa); fma4(acc0, xa.y, wb); fma4(acc0, xa.z, wc4); fma4(acc0, xa.w, wd);
        fma4(acc1, xb.x, wa); fma4(acc1, xb.y, wb); fma4(acc1, xb.z, wc4); fma4(acc1, xb.w, wd);
        fma4(acc2, xc.x, wa); fma4(acc2, xc.y, wb); fma4(acc2, xc.z, wc4); fma4(acc2, xc.w, wd);
        fma4(acc3, xd.x, wa); fma4(acc3, xd.y, wb); fma4(acc3, xd.z, wc4); fma4(acc3, xd.w, wd);
    }
    ushort4 o0 = {f2b(acc0.x), f2b(acc0.y), f2b(acc0.z), f2b(acc0.w)};
    ushort4 o1 = {f2b(acc1.x), f2b(acc1.y), f2b(acc1.z), f2b(acc1.w)};
    ushort4 o2 = {f2b(acc2.x), f2b(acc2.y), f2b(acc2.z), f2b(acc2.w)};
    ushort4 o3 = {f2b(acc3.x), f2b(acc3.y), f2b(acc3.z), f2b(acc3.w)};
    if (row0 + 0 < N_NODES) *(ushort4*)(y + (size_t)(row0 + 0) * NCLASS + c0) = o0;
    if (row0 + 1 < N_NODES) *(ushort4*)(y + (size_t)(row0 + 1) * NCLASS + c0) = o1;
    if (row0 + 2 < N_NODES) *(ushort4*)(y + (size_t)(row0 + 2) * NCLASS + c0) = o2;
    if (row0 + 3 < N_NODES) *(ushort4*)(y + (size_t)(row0 + 3) * NCLASS + c0) = o3;
}

// ---------------- fused aggregation passes (8-edges-per-load gather) ----------------
// Wave layout: lane = g*8 + sub. Group g (8 lanes) handles edge slot g of each
// 32-edge chunk; lane loads dwordx4 = 8 bf16 classes [sub*8, sub*8+8) of row col[p].
// One feature-load instruction gathers 8 edges (1 KB/instr) vs 1 edge (128 B) before.
// End: butterfly over lane-XOR {8,16,32} sums the 8 edge-groups.
// PASS 1: out = Âin, tout = Â·1 ; PASS 2: out = Âin, tout = Â·tin
// PASS 3: outf = softmax(Âin + t2*bv0 + t1*bv1 + b2)  (f32 output)
template <int PASS>
__global__ __launch_bounds__(256) void k_agg(
        const int* __restrict__ row_ptr, const int* __restrict__ col,
        const float* __restrict__ n_src, const float* __restrict__ n_dst,
        const ushort16* __restrict__ in, ushort16* __restrict__ out,
        float* __restrict__ outf,
        const float* __restrict__ tin, float* __restrict__ tout,
        const float* __restrict__ t1, const float* __restrict__ t2,
        const float* __restrict__ bv, const float* __restrict__ b2) {
    int wid = threadIdx.x >> 6, lane = threadIdx.x & 63;
    int node = blockIdx.x * 4 + wid;
    if (node >= N_NODES) return;
    int g = lane >> 3, sub = lane & 7;
    int s = row_ptr[node], e = row_ptr[node + 1];
    const uint4* inr = (const uint4*)in;   // row j = 8 uint4s

    float acc0 = 0.f, acc1 = 0.f, acc2 = 0.f, acc3 = 0.f;
    float acc4 = 0.f, acc5 = 0.f, acc6 = 0.f, acc7 = 0.f;
    float accs = 0.f;

#define CH(P)                                                                  \
    {                                                                          \
        int p_ = (P);                                                          \
        bool v_ = p_ < e;                                                      \
        int j_ = v_ ? col[p_] : 0;                                             \
        float ns_ = n_src[j_];                                                 \
        if (!v_) ns_ = 0.f;                                                    \
        uint4 u_ = inr[(size_t)j_ * 8 + sub];                                  \
        acc0 += ns_ * blo(u_.x); acc1 += ns_ * bhi(u_.x);                      \
        acc2 += ns_ * blo(u_.y); acc3 += ns_ * bhi(u_.y);                      \
        acc4 += ns_ * blo(u_.z); acc5 += ns_ * bhi(u_.z);                      \
        acc6 += ns_ * blo(u_.w); acc7 += ns_ * bhi(u_.w);                      \
        if (PASS == 1) accs += ns_;                                            \
        if (PASS == 2) accs += ns_ * tin[j_];                                  \
    }

    for (int base = s; base < e; base += 32) {
        CH(base + g)
        CH(base + 8 + g)
        CH(base + 16 + g)
        CH(base + 24 + g)
    }
#undef CH

    // reduce across the 8 edge-groups (lane bits 3..5)
#pragma unroll
    for (int off = 8; off <= 32; off <<= 1) {
        acc0 += __shfl_xor(acc0, off, 64);
        acc1 += __shfl_xor(acc1, off, 64);
        acc2 += __shfl_xor(acc2, off, 64);
        acc3 += __shfl_xor(acc3, off, 64);
        acc4 += __shfl_xor(acc4, off, 64);
        acc5 += __shfl_xor(acc5, off, 64);
        acc6 += __shfl_xor(acc6, off, 64);
        acc7 += __shfl_xor(acc7, off, 64);
        if (PASS != 3) accs += __shfl_xor(accs, off, 64);
    }

    float nd = n_dst[node];
    if (PASS == 3) {
        float t2n = t2[node], t1n = t1[node];
        const float* bvA = bv + sub * 8;
        const float* bvB = bv + 64 + sub * 8;
        const float* b2p = b2 + sub * 8;
        float v0 = acc0 * nd + t2n * bvA[0] + t1n * bvB[0] + b2p[0];
        float v1 = acc1 * nd + t2n * bvA[1] + t1n * bvB[1] + b2p[1];
        float v2 = acc2 * nd + t2n * bvA[2] + t1n * bvB[2] + b2p[2];
        float v3 = acc3 * nd + t2n * bvA[3] + t1n * bvB[3] + b2p[3];
        float v4 = acc4 * nd + t2n * bvA[4] + t1n * bvB[4] + b2p[4];
        float v5 = acc5 * nd + t2n * bvA[5] + t1n * bvB[5] + b2p[5];
        float v6 = acc6 * nd + t2n * bvA[6] + t1n * bvB[6] + b2p[6];
        float v7 = acc7 * nd + t2n * bvA[7] + t1n * bvB[7] + b2p[7];
        float m = fmaxf(fmaxf(fmaxf(v0, v1), fmaxf(v2, v3)),
                        fmaxf(fmaxf(v4, v5), fmaxf(v6, v7)));
#pragma unroll
        for (int off = 1; off <= 4; off <<= 1) m = fmaxf(m, __shfl_xor(m, off, 64));
        float e0 = __expf(v0 - m), e1 = __expf(v1 - m), e2 = __expf(v2 - m), e3 = __expf(v3 - m);
        float e4 = __expf(v4 - m), e5 = __expf(v5 - m), e6 = __expf(v6 - m), e7 = __expf(v7 - m);
        float sum = ((e0 + e1) + (e2 + e3)) + ((e4 + e5) + (e6 + e7));
#pragma unroll
        for (int off = 1; off <= 4; off <<= 1) sum += __shfl_xor(sum, off, 64);
        float r = 1.0f / sum;
        if (g == 0) {
            float4 o0 = {e0 * r, e1 * r, e2 * r, e3 * r};
            float4 o1 = {e4 * r, e5 * r, e6 * r, e7 * r};
            float4* op = (float4*)(outf + (size_t)node * NCLASS + sub * 8);
            op[0] = o0;
            op[1] = o1;
        }
    } else {
        if (g == 0) {
            uint32 w0 = (uint32)f2b(acc0 * nd) | ((uint32)f2b(acc1 * nd) << 16);
            uint32 w1 = (uint32)f2b(acc2 * nd) | ((uint32)f2b(acc3 * nd) << 16);
            uint32 w2 = (uint32)f2b(acc4 * nd) | ((uint32)f2b(acc5 * nd) << 16);
            uint32 w3 = (uint32)f2b(acc6 * nd) | ((uint32)f2b(acc7 * nd) << 16);
            uint4 w = {w0, w1, w2, w3};
            *((uint4*)(out + (size_t)node * NCLASS) + sub) = w;
        }
        if (lane == 0) tout[node] = accs * nd;
    }
}

extern "C" void kernel_launch(void* const* d_in, const int* in_sizes, int n_in,
                              void* d_out, int out_size, void* d_ws, size_t ws_size,
                              hipStream_t stream) {
    const float* x   = (const float*)d_in[0];
    const int*   src = (const int*)d_in[1];
    const int*   dst = (const int*)d_in[2];
    const float* W0  = (const float*)d_in[3];
    const float* b0  = (const float*)d_in[4];
    const float* W1  = (const float*)d_in[5];
    const float* b1  = (const float*)d_in[6];
    const float* W2  = (const float*)d_in[7];
    const float* b2  = (const float*)d_in[8];
    float* out = (float*)d_out;

    size_t off = 0;
    auto alloc = [&](size_t bytes) {
        void* p = (char*)d_ws + off;
        off = (off + bytes + 255) & ~(size_t)255;
        return p;
    };
    int*      deg_in   = (int*)alloc(N_NODES * 4);
    float*    n_src    = (float*)alloc(N_NODES * 4);
    float*    n_dst    = (float*)alloc(N_NODES * 4);
    int*      row_ptr  = (int*)alloc((N_NODES + 1) * 4);
    int*      blk_sums = (int*)alloc((NB_SCAN + 1) * 4);
    int*      col      = (int*)alloc((size_t)N_EDGES * 4);
    uint32*   scratch  = (uint32*)alloc((size_t)8 * NSL * RANGE * 4);   // 25.6 MB
    float*    W01      = (float*)alloc(NFEAT * NHID * 4);
    float*    Wc       = (float*)alloc(NFEAT * NCLASS * 4);
    float*    bv       = (float*)alloc(128 * 4);
    float*    t1       = (float*)alloc(N_NODES * 4);
    float*    t2       = (float*)alloc(N_NODES * 4);
    ushort16* bufB1    = (ushort16*)alloc((size_t)N_NODES * NCLASS * 2);  // 12.8 MB bf16
    ushort16* bufB2    = (ushort16*)alloc((size_t)N_NODES * NCLASS * 2);  // 12.8 MB bf16
    (void)ws_size; (void)in_sizes; (void)n_in; (void)out_size;

    const int TB = 256;
    const int NBn = (N_NODES + TB - 1) / TB;
    const int NW = (N_NODES + 3) / 4;   // wave-per-node kernels
    const int GP = 8 * NSL;             // 512 blocks for hist/fill

    k_hist<<<GP, TB, 0, stream>>>((const int4*)src, (const int4*)dst, scratch);
    k_sumdeg<<<NBn, TB, 0, stream>>>(scratch, deg_in, n_src, n_dst);
    k_scan1<<<NB_SCAN, SCAN_B, 0, stream>>>(deg_in, row_ptr, blk_sums);
    k_scan2<<<1, 64, 0, stream>>>(blk_sums);
    k_scan3<<<NB_SCAN, SCAN_B, 0, stream>>>(blk_sums, row_ptr);
    k_offsets<<<NBn, TB, 0, stream>>>(scratch, row_ptr);
    k_fill2<<<GP, TB, 0, stream>>>((const int4*)src, (const int4*)dst, scratch, col);

    k_w01<<<NFEAT, NHID, 0, stream>>>(W0, W1, W01);
    k_wc<<<NFEAT, NCLASS, 0, stream>>>(W01, W2, Wc);
    k_bv<<<1, NCLASS, 0, stream>>>(b0, W1, b1, W2, bv);

    // Y -> B1 (bf16); Z1 -> B2 (+t1); Z2 -> B1 (+t2); pass3: B1 -> softmax -> OUT (f32)
    k_gemm_y<<<(N_NODES + 63) / 64, 256, 0, stream>>>(x, Wc, bufB1);

    k_agg<1><<<NW, 256, 0, stream>>>(row_ptr, col, n_src, n_dst, bufB1, bufB2, nullptr,
                                     nullptr, t1, nullptr, nullptr, nullptr, nullptr);
    k_agg<2><<<NW, 256, 0, stream>>>(row_ptr, col, n_src, n_dst, bufB2, bufB1, nullptr,
                                     t1, t2, nullptr, nullptr, nullptr, nullptr);
    k_agg<3><<<NW, 256, 0, stream>>>(row_ptr, col, n_src, n_dst, bufB1, nullptr, out,
                                     nullptr, nullptr, t1, t2, bv, b2);
}

// Round 3
// 577.825 us; speedup vs baseline: 1.0704x; 1.0704x over previous
//
#include <hip/hip_runtime.h>
#include <hip/hip_bf16.h>

#define N_NODES 100000
#define N_EDGES 3200000
#define NFEAT 256
#define NHID 128
#define NCLASS 64
#define SCAN_B 1024
#define NB_SCAN ((N_NODES + SCAN_B - 1) / SCAN_B)   // 98
#define NVEC4 (N_EDGES / 4)                          // 800000
#define RANGE (N_NODES / 8)                          // 12500 nodes per group
#define NSL 64                                       // edge slices per group

typedef unsigned int uint32;
typedef unsigned short ushort16;

// hand-rolled bf16 (RNE) — intermediates only, finite values
static __device__ __forceinline__ float b2f(ushort16 u) {
    union { float f; uint32 i; } c; c.i = ((uint32)u) << 16; return c.f;
}
static __device__ __forceinline__ ushort16 f2b(float f) {
    union { float f; uint32 i; } c; c.f = f;
    uint32 r = (c.i + 0x7FFFu + ((c.i >> 16) & 1u)) >> 16;
    return (ushort16)r;
}
// unpack bf16 pair packed in a uint32 (little-endian: low ushort = even class)
static __device__ __forceinline__ float blo(uint32 u) {
    union { float f; uint32 i; } c; c.i = u << 16; return c.f;
}
static __device__ __forceinline__ float bhi(uint32 u) {
    union { float f; uint32 i; } c; c.i = u & 0xFFFF0000u; return c.f;
}

// ---------------- phase A: LDS-privatized histogram ----------------
__global__ __launch_bounds__(256) void k_hist(const int4* __restrict__ src4,
                                              const int4* __restrict__ dst4,
                                              uint32* __restrict__ scratch) {
    __shared__ uint32 h[RANGE];   // 50 KB
    int g = blockIdx.x & 7, sl = blockIdx.x >> 3;
    int lo = g * RANGE, hi = lo + RANGE;
    for (int i = threadIdx.x; i < RANGE; i += 256) h[i] = 0u;
    __syncthreads();
    for (int t = sl * 256 + threadIdx.x; t < NVEC4; t += NSL * 256) {
        int4 s = src4[t], d = dst4[t];
        if (s.x >= lo && s.x < hi) atomicAdd(&h[s.x - lo], 1u);
        if (s.y >= lo && s.y < hi) atomicAdd(&h[s.y - lo], 1u);
        if (s.z >= lo && s.z < hi) atomicAdd(&h[s.z - lo], 1u);
        if (s.w >= lo && s.w < hi) atomicAdd(&h[s.w - lo], 1u);
        if (d.x >= lo && d.x < hi) atomicAdd(&h[d.x - lo], 65536u);
        if (d.y >= lo && d.y < hi) atomicAdd(&h[d.y - lo], 65536u);
        if (d.z >= lo && d.z < hi) atomicAdd(&h[d.z - lo], 65536u);
        if (d.w >= lo && d.w < hi) atomicAdd(&h[d.w - lo], 65536u);
    }
    __syncthreads();
    uint32* dstp = scratch + ((size_t)(g * NSL + sl)) * RANGE;
    for (int i = threadIdx.x; i < RANGE; i += 256) dstp[i] = h[i];
}

// ---------------- reduce per-block counts -> degrees + norms ----------------
__global__ void k_sumdeg(const uint32* __restrict__ scratch, int* __restrict__ deg_in,
                         float* __restrict__ n_src, float* __restrict__ n_dst) {
    int i = blockIdx.x * blockDim.x + threadIdx.x;
    if (i >= N_NODES) return;
    int g = i / RANGE, r = i - g * RANGE;
    const uint32* base = scratch + (size_t)g * NSL * RANGE + r;
    uint32 so = 0, di = 0;
    for (int s = 0; s < NSL; s++) {
        uint32 v = base[(size_t)s * RANGE];
        so += v & 0xFFFFu;
        di += v >> 16;
    }
    deg_in[i] = (int)di;
    uint32 so1 = so < 1u ? 1u : so;
    uint32 di1 = di < 1u ? 1u : di;
    n_src[i] = rsqrtf((float)so1);
    n_dst[i] = rsqrtf((float)di1);
}

// ---------------- scan (3-pass) over deg_in -> row_ptr ----------------
__global__ void k_scan1(const int* __restrict__ deg_in, int* __restrict__ row_ptr,
                        int* __restrict__ blk_sums) {
    __shared__ int sh[SCAN_B];
    int i = blockIdx.x * SCAN_B + threadIdx.x;
    int v = (i < N_NODES) ? deg_in[i] : 0;
    sh[threadIdx.x] = v;
    __syncthreads();
    for (int o = 1; o < SCAN_B; o <<= 1) {
        int t = 0;
        if ((int)threadIdx.x >= o) t = sh[threadIdx.x - o];
        __syncthreads();
        sh[threadIdx.x] += t;
        __syncthreads();
    }
    if (i < N_NODES) row_ptr[i] = sh[threadIdx.x] - v;   // exclusive within block
    if (threadIdx.x == SCAN_B - 1) blk_sums[blockIdx.x] = sh[SCAN_B - 1];
}

__global__ void k_scan2(int* __restrict__ blk_sums) {
    if (threadIdx.x == 0 && blockIdx.x == 0) {
        int acc = 0;
        for (int b = 0; b < NB_SCAN; b++) { int v = blk_sums[b]; blk_sums[b] = acc; acc += v; }
        blk_sums[NB_SCAN] = acc;
    }
}

__global__ void k_scan3(const int* __restrict__ blk_sums, int* __restrict__ row_ptr) {
    int i = blockIdx.x * SCAN_B + threadIdx.x;
    if (i < N_NODES) row_ptr[i] += blk_sums[blockIdx.x];
    if (i == 0) row_ptr[N_NODES] = blk_sums[NB_SCAN];
}

// ---------------- per-(g,slice) cursor start offsets (in-place on scratch) ----------------
__global__ void k_offsets(uint32* __restrict__ scratch, const int* __restrict__ row_ptr) {
    int i = blockIdx.x * blockDim.x + threadIdx.x;
    if (i >= N_NODES) return;
    int g = i / RANGE, r = i - g * RANGE;
    uint32* base = scratch + (size_t)g * NSL * RANGE + r;
    uint32 run = (uint32)row_ptr[i];
    for (int s = 0; s < NSL; s++) {
        uint32 v = base[(size_t)s * RANGE];
        base[(size_t)s * RANGE] = run;
        run += v >> 16;
    }
}

// ---------------- phase B: atomic-free counting-sort fill ----------------
__global__ __launch_bounds__(256) void k_fill2(const int4* __restrict__ src4,
                                               const int4* __restrict__ dst4,
                                               const uint32* __restrict__ scratch,
                                               int* __restrict__ col) {
    __shared__ uint32 cur[RANGE];   // 50 KB
    int g = blockIdx.x & 7, sl = blockIdx.x >> 3;
    int lo = g * RANGE, hi = lo + RANGE;
    const uint32* base = scratch + ((size_t)(g * NSL + sl)) * RANGE;
    for (int i = threadIdx.x; i < RANGE; i += 256) cur[i] = base[i];
    __syncthreads();
    for (int t = sl * 256 + threadIdx.x; t < NVEC4; t += NSL * 256) {
        int4 s = src4[t], d = dst4[t];
        if (d.x >= lo && d.x < hi) { uint32 p = atomicAdd(&cur[d.x - lo], 1u); col[p] = s.x; }
        if (d.y >= lo && d.y < hi) { uint32 p = atomicAdd(&cur[d.y - lo], 1u); col[p] = s.y; }
        if (d.z >= lo && d.z < hi) { uint32 p = atomicAdd(&cur[d.z - lo], 1u); col[p] = s.z; }
        if (d.w >= lo && d.w < hi) { uint32 p = atomicAdd(&cur[d.w - lo], 1u); col[p] = s.w; }
    }
}

// ---------------- tiny weight-collapse GEMMs ----------------
__global__ void k_w01(const float* __restrict__ W0, const float* __restrict__ W1,
                      float* __restrict__ W01) {
    __shared__ float row[NHID];
    int r = blockIdx.x, c = threadIdx.x;   // 128 threads
    row[c] = W0[r * NHID + c];
    __syncthreads();
    float acc = 0.f;
    for (int k = 0; k < NHID; k++) acc += row[k] * W1[k * NHID + c];
    W01[r * NHID + c] = acc;
}

__global__ void k_wc(const float* __restrict__ W01, const float* __restrict__ W2,
                     float* __restrict__ Wc) {
    __shared__ float row[NHID];
    int r = blockIdx.x, c = threadIdx.x;   // 64 threads
    row[c] = W01[r * NHID + c];
    row[c + 64] = W01[r * NHID + c + 64];
    __syncthreads();
    float acc = 0.f;
    for (int k = 0; k < NHID; k++) acc += row[k] * W2[k * NCLASS + c];
    Wc[r * NCLASS + c] = acc;
}

// bv[0..63] = b0@W1@W2, bv[64..127] = b1@W2
__global__ void k_bv(const float* __restrict__ b0, const float* __restrict__ W1,
                     const float* __restrict__ b1, const float* __restrict__ W2,
                     float* __restrict__ bv) {
    __shared__ float tmp[NHID];
    int c = threadIdx.x;   // 64 threads
    for (int cc = c; cc < NHID; cc += 64) {
        float a = 0.f;
        for (int k = 0; k < NHID; k++) a += b0[k] * W1[k * NHID + cc];
        tmp[cc] = a;
    }
    __syncthreads();
    float a1 = 0.f, a2 = 0.f;
    for (int k = 0; k < NHID; k++) {
        float wv = W2[k * NCLASS + c];
        a1 += tmp[k] * wv;
        a2 += b1[k] * wv;
    }
    bv[c] = a1;
    bv[64 + c] = a2;
}

// ---------------- main GEMM: y = x @ Wc  [N,256]x[256,64], bf16 output ----------------
// Weights staged in LDS in TWO 128-k halves (32 KB) instead of one 64 KB tile:
// LDS then admits 5 blocks/CU (vs 2), VGPR ~88 admits 5 waves/SIMD -> ~60%
// occupancy, which is what hides the streaming x-load latency. (R1 experiment:
// dropping LDS entirely regressed 107->141 us — global weight loads doubled the
// per-wave VMEM chain. Keep weights in LDS.)
static __device__ __forceinline__ void fma4(float4& a, float xs, const float4& wv) {
    a.x += xs * wv.x; a.y += xs * wv.y; a.z += xs * wv.z; a.w += xs * wv.w;
}
__global__ __launch_bounds__(256) void k_gemm_y(const float* __restrict__ x,
                                                const float* __restrict__ Wc,
                                                ushort16* __restrict__ y) {
    __shared__ float w_sh[128][NCLASS];   // 32 KB
    int tid = threadIdx.x;
    int tx = tid & 15, ty = tid >> 4;
    int row0 = blockIdx.x * 64 + ty * 4;
    int c0 = tx * 4;
    int r0 = min(row0 + 0, N_NODES - 1);
    int r1 = min(row0 + 1, N_NODES - 1);
    int r2 = min(row0 + 2, N_NODES - 1);
    int r3 = min(row0 + 3, N_NODES - 1);
    const float* xp0 = x + (size_t)r0 * NFEAT;
    const float* xp1 = x + (size_t)r1 * NFEAT;
    const float* xp2 = x + (size_t)r2 * NFEAT;
    const float* xp3 = x + (size_t)r3 * NFEAT;
    const float4* wsrc = (const float4*)Wc;   // [256*64/4] float4s
    float4* wdst = (float4*)&w_sh[0][0];      // [128*64/4] float4s
    float4 acc0 = {0, 0, 0, 0}, acc1 = {0, 0, 0, 0}, acc2 = {0, 0, 0, 0}, acc3 = {0, 0, 0, 0};
    float4 xa = *(const float4*)(xp0);
    float4 xb = *(const float4*)(xp1);
    float4 xc = *(const float4*)(xp2);
    float4 xd = *(const float4*)(xp3);
#pragma unroll
    for (int half = 0; half < 2; half++) {
        const int kb = half * 128;
        if (half) __syncthreads();   // previous tile fully consumed
        for (int i = tid; i < 128 * NCLASS / 4; i += 256)
            wdst[i] = wsrc[kb * (NCLASS / 4) + i];
        __syncthreads();
#pragma unroll 4
        for (int k = kb; k < kb + 128; k += 4) {
            float4 ca = xa, cb = xb, cc = xc, cd = xd;
            if (k + 4 < NFEAT) {
                xa = *(const float4*)(xp0 + k + 4);
                xb = *(const float4*)(xp1 + k + 4);
                xc = *(const float4*)(xp2 + k + 4);
                xd = *(const float4*)(xp3 + k + 4);
            }
            int kl = k - kb;
            float4 w0 = *(const float4*)&w_sh[kl + 0][c0];
            float4 w1 = *(const float4*)&w_sh[kl + 1][c0];
            float4 w2 = *(const float4*)&w_sh[kl + 2][c0];
            float4 w3 = *(const float4*)&w_sh[kl + 3][c0];
            fma4(acc0, ca.x, w0); fma4(acc0, ca.y, w1); fma4(acc0, ca.z, w2); fma4(acc0, ca.w, w3);
            fma4(acc1, cb.x, w0); fma4(acc1, cb.y, w1); fma4(acc1, cb.z, w2); fma4(acc1, cb.w, w3);
            fma4(acc2, cc.x, w0); fma4(acc2, cc.y, w1); fma4(acc2, cc.z, w2); fma4(acc2, cc.w, w3);
            fma4(acc3, cd.x, w0); fma4(acc3, cd.y, w1); fma4(acc3, cd.z, w2); fma4(acc3, cd.w, w3);
        }
    }
    ushort4 o0 = {f2b(acc0.x), f2b(acc0.y), f2b(acc0.z), f2b(acc0.w)};
    ushort4 o1 = {f2b(acc1.x), f2b(acc1.y), f2b(acc1.z), f2b(acc1.w)};
    ushort4 o2 = {f2b(acc2.x), f2b(acc2.y), f2b(acc2.z), f2b(acc2.w)};
    ushort4 o3 = {f2b(acc3.x), f2b(acc3.y), f2b(acc3.z), f2b(acc3.w)};
    if (row0 + 0 < N_NODES) *(ushort4*)(y + (size_t)(row0 + 0) * NCLASS + c0) = o0;
    if (row0 + 1 < N_NODES) *(ushort4*)(y + (size_t)(row0 + 1) * NCLASS + c0) = o1;
    if (row0 + 2 < N_NODES) *(ushort4*)(y + (size_t)(row0 + 2) * NCLASS + c0) = o2;
    if (row0 + 3 < N_NODES) *(ushort4*)(y + (size_t)(row0 + 3) * NCLASS + c0) = o3;
}

// ---------------- fused aggregation passes (8-edges-per-load gather) ----------------
// Wave layout: lane = g*8 + sub. Group g (8 lanes) handles edge slot g of each
// 32-edge chunk; lane loads dwordx4 = 8 bf16 classes [sub*8, sub*8+8) of row col[p].
// One feature-load instruction gathers 8 edges (1 KB/instr) vs 1 edge (128 B) before.
// End: butterfly over lane-XOR {8,16,32} sums the 8 edge-groups.
// PASS 1: out = Âin, tout = Â·1 ; PASS 2: out = Âin, tout = Â·tin
// PASS 3: outf = softmax(Âin + t2*bv0 + t1*bv1 + b2)  (f32 output)
template <int PASS>
__global__ __launch_bounds__(256) void k_agg(
        const int* __restrict__ row_ptr, const int* __restrict__ col,
        const float* __restrict__ n_src, const float* __restrict__ n_dst,
        const ushort16* __restrict__ in, ushort16* __restrict__ out,
        float* __restrict__ outf,
        const float* __restrict__ tin, float* __restrict__ tout,
        const float* __restrict__ t1, const float* __restrict__ t2,
        const float* __restrict__ bv, const float* __restrict__ b2) {
    int wid = threadIdx.x >> 6, lane = threadIdx.x & 63;
    int node = blockIdx.x * 4 + wid;
    if (node >= N_NODES) return;
    int g = lane >> 3, sub = lane & 7;
    int s = row_ptr[node], e = row_ptr[node + 1];
    const uint4* inr = (const uint4*)in;   // row j = 8 uint4s

    float acc0 = 0.f, acc1 = 0.f, acc2 = 0.f, acc3 = 0.f;
    float acc4 = 0.f, acc5 = 0.f, acc6 = 0.f, acc7 = 0.f;
    float accs = 0.f;

#define CH(P)                                                                  \
    {                                                                          \
        int p_ = (P);                                                          \
        bool v_ = p_ < e;                                                      \
        int j_ = v_ ? col[p_] : 0;                                             \
        float ns_ = n_src[j_];                                                 \
        if (!v_) ns_ = 0.f;                                                    \
        uint4 u_ = inr[(size_t)j_ * 8 + sub];                                  \
        acc0 += ns_ * blo(u_.x); acc1 += ns_ * bhi(u_.x);                      \
        acc2 += ns_ * blo(u_.y); acc3 += ns_ * bhi(u_.y);                      \
        acc4 += ns_ * blo(u_.z); acc5 += ns_ * bhi(u_.z);                      \
        acc6 += ns_ * blo(u_.w); acc7 += ns_ * bhi(u_.w);                      \
        if (PASS == 1) accs += ns_;                                            \
        if (PASS == 2) accs += ns_ * tin[j_];                                  \
    }

    for (int base = s; base < e; base += 32) {
        CH(base + g)
        CH(base + 8 + g)
        CH(base + 16 + g)
        CH(base + 24 + g)
    }
#undef CH

    // reduce across the 8 edge-groups (lane bits 3..5)
#pragma unroll
    for (int off = 8; off <= 32; off <<= 1) {
        acc0 += __shfl_xor(acc0, off, 64);
        acc1 += __shfl_xor(acc1, off, 64);
        acc2 += __shfl_xor(acc2, off, 64);
        acc3 += __shfl_xor(acc3, off, 64);
        acc4 += __shfl_xor(acc4, off, 64);
        acc5 += __shfl_xor(acc5, off, 64);
        acc6 += __shfl_xor(acc6, off, 64);
        acc7 += __shfl_xor(acc7, off, 64);
        if (PASS != 3) accs += __shfl_xor(accs, off, 64);
    }

    float nd = n_dst[node];
    if (PASS == 3) {
        float t2n = t2[node], t1n = t1[node];
        const float* bvA = bv + sub * 8;
        const float* bvB = bv + 64 + sub * 8;
        const float* b2p = b2 + sub * 8;
        float v0 = acc0 * nd + t2n * bvA[0] + t1n * bvB[0] + b2p[0];
        float v1 = acc1 * nd + t2n * bvA[1] + t1n * bvB[1] + b2p[1];
        float v2 = acc2 * nd + t2n * bvA[2] + t1n * bvB[2] + b2p[2];
        float v3 = acc3 * nd + t2n * bvA[3] + t1n * bvB[3] + b2p[3];
        float v4 = acc4 * nd + t2n * bvA[4] + t1n * bvB[4] + b2p[4];
        float v5 = acc5 * nd + t2n * bvA[5] + t1n * bvB[5] + b2p[5];
        float v6 = acc6 * nd + t2n * bvA[6] + t1n * bvB[6] + b2p[6];
        float v7 = acc7 * nd + t2n * bvA[7] + t1n * bvB[7] + b2p[7];
        float m = fmaxf(fmaxf(fmaxf(v0, v1), fmaxf(v2, v3)),
                        fmaxf(fmaxf(v4, v5), fmaxf(v6, v7)));
#pragma unroll
        for (int off = 1; off <= 4; off <<= 1) m = fmaxf(m, __shfl_xor(m, off, 64));
        float e0 = __expf(v0 - m), e1 = __expf(v1 - m), e2 = __expf(v2 - m), e3 = __expf(v3 - m);
        float e4 = __expf(v4 - m), e5 = __expf(v5 - m), e6 = __expf(v6 - m), e7 = __expf(v7 - m);
        float sum = ((e0 + e1) + (e2 + e3)) + ((e4 + e5) + (e6 + e7));
#pragma unroll
        for (int off = 1; off <= 4; off <<= 1) sum += __shfl_xor(sum, off, 64);
        float r = 1.0f / sum;
        if (g == 0) {
            float4 o0 = {e0 * r, e1 * r, e2 * r, e3 * r};
            float4 o1 = {e4 * r, e5 * r, e6 * r, e7 * r};
            float4* op = (float4*)(outf + (size_t)node * NCLASS + sub * 8);
            op[0] = o0;
            op[1] = o1;
        }
    } else {
        if (g == 0) {
            uint32 w0 = (uint32)f2b(acc0 * nd) | ((uint32)f2b(acc1 * nd) << 16);
            uint32 w1 = (uint32)f2b(acc2 * nd) | ((uint32)f2b(acc3 * nd) << 16);
            uint32 w2 = (uint32)f2b(acc4 * nd) | ((uint32)f2b(acc5 * nd) << 16);
            uint32 w3 = (uint32)f2b(acc6 * nd) | ((uint32)f2b(acc7 * nd) << 16);
            uint4 w = {w0, w1, w2, w3};
            *((uint4*)(out + (size_t)node * NCLASS) + sub) = w;
        }
        if (lane == 0) tout[node] = accs * nd;
    }
}

extern "C" void kernel_launch(void* const* d_in, const int* in_sizes, int n_in,
                              void* d_out, int out_size, void* d_ws, size_t ws_size,
                              hipStream_t stream) {
    const float* x   = (const float*)d_in[0];
    const int*   src = (const int*)d_in[1];
    const int*   dst = (const int*)d_in[2];
    const float* W0  = (const float*)d_in[3];
    const float* b0  = (const float*)d_in[4];
    const float* W1  = (const float*)d_in[5];
    const float* b1  = (const float*)d_in[6];
    const float* W2  = (const float*)d_in[7];
    const float* b2  = (const float*)d_in[8];
    float* out = (float*)d_out;

    size_t off = 0;
    auto alloc = [&](size_t bytes) {
        void* p = (char*)d_ws + off;
        off = (off + bytes + 255) & ~(size_t)255;
        return p;
    };
    int*      deg_in   = (int*)alloc(N_NODES * 4);
    float*    n_src    = (float*)alloc(N_NODES * 4);
    float*    n_dst    = (float*)alloc(N_NODES * 4);
    int*      row_ptr  = (int*)alloc((N_NODES + 1) * 4);
    int*      blk_sums = (int*)alloc((NB_SCAN + 1) * 4);
    int*      col      = (int*)alloc((size_t)N_EDGES * 4);
    uint32*   scratch  = (uint32*)alloc((size_t)8 * NSL * RANGE * 4);   // 25.6 MB
    float*    W01      = (float*)alloc(NFEAT * NHID * 4);
    float*    Wc       = (float*)alloc(NFEAT * NCLASS * 4);
    float*    bv       = (float*)alloc(128 * 4);
    float*    t1       = (float*)alloc(N_NODES * 4);
    float*    t2       = (float*)alloc(N_NODES * 4);
    ushort16* bufB1    = (ushort16*)alloc((size_t)N_NODES * NCLASS * 2);  // 12.8 MB bf16
    ushort16* bufB2    = (ushort16*)alloc((size_t)N_NODES * NCLASS * 2);  // 12.8 MB bf16
    (void)ws_size; (void)in_sizes; (void)n_in; (void)out_size;

    const int TB = 256;
    const int NBn = (N_NODES + TB - 1) / TB;
    const int NW = (N_NODES + 3) / 4;   // wave-per-node kernels
    const int GP = 8 * NSL;             // 512 blocks for hist/fill

    k_hist<<<GP, TB, 0, stream>>>((const int4*)src, (const int4*)dst, scratch);
    k_sumdeg<<<NBn, TB, 0, stream>>>(scratch, deg_in, n_src, n_dst);
    k_scan1<<<NB_SCAN, SCAN_B, 0, stream>>>(deg_in, row_ptr, blk_sums);
    k_scan2<<<1, 64, 0, stream>>>(blk_sums);
    k_scan3<<<NB_SCAN, SCAN_B, 0, stream>>>(blk_sums, row_ptr);
    k_offsets<<<NBn, TB, 0, stream>>>(scratch, row_ptr);
    k_fill2<<<GP, TB, 0, stream>>>((const int4*)src, (const int4*)dst, scratch, col);

    k_w01<<<NFEAT, NHID, 0, stream>>>(W0, W1, W01);
    k_wc<<<NFEAT, NCLASS, 0, stream>>>(W01, W2, Wc);
    k_bv<<<1, NCLASS, 0, stream>>>(b0, W1, b1, W2, bv);

    // Y -> B1 (bf16); Z1 -> B2 (+t1); Z2 -> B1 (+t2); pass3: B1 -> softmax -> OUT (f32)
    k_gemm_y<<<(N_NODES + 63) / 64, 256, 0, stream>>>(x, Wc, bufB1);

    k_agg<1><<<NW, 256, 0, stream>>>(row_ptr, col, n_src, n_dst, bufB1, bufB2, nullptr,
                                     nullptr, t1, nullptr, nullptr, nullptr, nullptr);
    k_agg<2><<<NW, 256, 0, stream>>>(row_ptr, col, n_src, n_dst, bufB2, bufB1, nullptr,
                                     t1, t2, nullptr, nullptr, nullptr, nullptr);
    k_agg<3><<<NW, 256, 0, stream>>>(row_ptr, col, n_src, n_dst, bufB1, nullptr, out,
                                     nullptr, nullptr, t1, t2, bv, b2);
}